// Round 8
// baseline (1203.780 us; speedup 1.0000x reference)
//
#include <hip/hip_runtime.h>

#define N_NODES 100000
#define M_PAD   100096   // 782 * 128
#define N_MBLK  782
#define N_EDGES 1600000
#define N_GRAPHS 64
#define HID 256
#define PROJ 128
#define NLAYERS 4

#define EBUF_STRIDE 8192
#define N_BUCKETS ((N_NODES + 255) / 256)  // 391
#define CSR_BLK 1024
#define EPT 10
#define CSR_NBLK ((N_EDGES + CSR_BLK * EPT - 1) / (CSR_BLK * EPT))  // 157
#define SENT 0xFFFFFFFFu

typedef unsigned short u16;
typedef unsigned long long u64;
typedef __attribute__((ext_vector_type(4))) float f32x4;
typedef __attribute__((ext_vector_type(2))) float vf2;

__device__ __forceinline__ void gload16(const void* g, void* l) {
  __builtin_amdgcn_global_load_lds((const __attribute__((address_space(1))) void*)g,
                                   (__attribute__((address_space(3))) void*)l, 16, 0, 0);
}
// ---- fp8 e4m3 (HW cvt; encode/decode self-consistent) ----
__device__ __forceinline__ unsigned pack_fp8x4(float a, float b, float c, float d) {
  int v = __builtin_amdgcn_cvt_pk_fp8_f32(a, b, 0, false);
  v = __builtin_amdgcn_cvt_pk_fp8_f32(c, d, v, true);
  return (unsigned)v;
}
__device__ __forceinline__ unsigned char f2f8(float a) {
  return (unsigned char)(__builtin_amdgcn_cvt_pk_fp8_f32(a, a, 0, false) & 0xFF);
}
__device__ __forceinline__ void accf8(float* a, unsigned w) {
  vf2 lo = __builtin_amdgcn_cvt_pk_f32_fp8((int)w, false);
  vf2 hi = __builtin_amdgcn_cvt_pk_f32_fp8((int)w, true);
  a[0] += lo.x; a[1] += lo.y; a[2] += hi.x; a[3] += hi.y;
}
__device__ __forceinline__ void decf8(float* f, unsigned w) {
  vf2 lo = __builtin_amdgcn_cvt_pk_f32_fp8((int)w, false);
  vf2 hi = __builtin_amdgcn_cvt_pk_f32_fp8((int)w, true);
  f[0] = lo.x; f[1] = lo.y; f[2] = hi.x; f[3] = hi.y;
}

// ---------------------------------------------------------------- CSR -------
__global__ __launch_bounds__(1024) void bucket_scatter(
    const int* __restrict__ src, const int* __restrict__ dst,
    u64* __restrict__ bfill64, uint2* __restrict__ ebuf) {
  __shared__ int lhist[N_BUCKETS];
  __shared__ int lbase[N_BUCKETS];
  int t = threadIdx.x;
  int e0 = blockIdx.x * (CSR_BLK * EPT) + t;
  for (int i = t; i < N_BUCKETS; i += CSR_BLK) lhist[i] = 0;
  __syncthreads();
  int sv[EPT], dv[EPT];
#pragma unroll
  for (int j = 0; j < EPT; j++) {
    int e = e0 + j * CSR_BLK;
    if (e < N_EDGES) {
      sv[j] = src[e];
      dv[j] = dst[e];
      atomicAdd(&lhist[dv[j] >> 8], 1);
    } else {
      dv[j] = -1;
      sv[j] = 0;
    }
  }
  __syncthreads();
  for (int i = t; i < N_BUCKETS; i += CSR_BLK) {
    int c = lhist[i];
    if (c > 0) {
      int rounded = (c + 7) & ~7;  // 8 slots = 64B line alignment
      u64 old = atomicAdd(&bfill64[(size_t)i * 8],
                          ((u64)rounded << 32) | (u64)c);
      int base = (int)(old >> 32);
      lbase[i] = base;
      for (int k = c; k < rounded; k++) {  // self-write pad sentinels
        int p = base + k;
        if (p < EBUF_STRIDE) {
          uint2 q; q.x = 0; q.y = SENT;
          ebuf[(size_t)i * EBUF_STRIDE + p] = q;
        }
      }
      lhist[i] = 0;  // reuse as block-local fill cursor
    }
  }
  __syncthreads();
#pragma unroll
  for (int j = 0; j < EPT; j++) {
    if (dv[j] >= 0) {
      int b = dv[j] >> 8;
      int p = lbase[b] + atomicAdd(&lhist[b], 1);
      if (p < EBUF_STRIDE) {  // ~47-sigma margin; drop-safe guard
        uint2 q;
        q.x = (unsigned)sv[j];
        q.y = (unsigned)dv[j];
        ebuf[(size_t)b * EBUF_STRIDE + p] = q;
      }
    }
  }
}

__global__ __launch_bounds__(512) void bucket_prefix(
    const u64* __restrict__ bfill64, int* __restrict__ bucket_base,
    int* __restrict__ row_ptr) {
  __shared__ int tile[512];
  int t = threadIdx.x;
  int v = 0;
  if (t < N_BUCKETS) {
    u64 w = bfill64[(size_t)t * 8];
    v = (int)(w & 0xFFFFFFFFull);
    if ((int)(w >> 32) > EBUF_STRIDE) v = min(v, EBUF_STRIDE);  // degenerate clamp
  }
  tile[t] = v;
  __syncthreads();
  for (int off = 1; off < 512; off <<= 1) {
    int add = (t >= off) ? tile[t - off] : 0;
    __syncthreads();
    tile[t] += add;
    __syncthreads();
  }
  if (t < N_BUCKETS) bucket_base[t] = tile[t] - v;  // exclusive
  if (t == N_BUCKETS - 1) row_ptr[N_NODES] = tile[t];
}

__global__ __launch_bounds__(1024) void csr_build(
    const uint2* __restrict__ ebuf, const u64* __restrict__ bfill64,
    const int* __restrict__ bucket_base, int* __restrict__ row_ptr,
    float* __restrict__ inv_cnt, int* __restrict__ col) {
  __shared__ int hist[256];
  __shared__ int nscan[256];
  __shared__ int cursor[256];
  int b = blockIdx.x;
  int t = threadIdx.x;
  int nalloc = min((int)(bfill64[(size_t)b * 8] >> 32), EBUF_STRIDE);
  int bbase = bucket_base[b];
  if (t < 256) hist[t] = 0;
  __syncthreads();
  uint2 q[8];
#pragma unroll
  for (int k = 0; k < 8; k++) {
    int i = t + k * CSR_BLK;
    q[k].x = 0; q[k].y = SENT;
    if (i < nalloc) {
      q[k] = ebuf[(size_t)b * EBUF_STRIDE + i];
      if (q[k].y != SENT) atomicAdd(&hist[q[k].y & 255], 1);
    }
  }
  __syncthreads();
  if (t < 256) nscan[t] = hist[t];
  __syncthreads();
  for (int off = 1; off < 256; off <<= 1) {
    int add = 0;
    if (t < 256 && t >= off) add = nscan[t - off];
    __syncthreads();
    if (t < 256) nscan[t] += add;
    __syncthreads();
  }
  int nb = min(256, N_NODES - b * 256);
  if (t < 256) {
    int excl = nscan[t] - hist[t];
    cursor[t] = excl;
    if (t < nb) {
      row_ptr[b * 256 + t] = bbase + excl;
      inv_cnt[b * 256 + t] = 1.0f / fmaxf((float)hist[t], 1.0f);
    }
  }
  __syncthreads();
#pragma unroll
  for (int k = 0; k < 8; k++) {
    if (q[k].y != SENT) {
      int l = (int)(q[k].y & 255);
      int pos = bbase + atomicAdd(&cursor[l], 1);
      col[pos] = (int)q[k].x;
    }
  }
}

// ------------------------------------------------------------ converts ------
__global__ __launch_bounds__(256) void convert_x8(const float4* __restrict__ x,
                                                  unsigned* __restrict__ h8) {
  int i = blockIdx.x * blockDim.x + threadIdx.x;  // exactly N_NODES*64 threads
  float4 v = x[i];
  h8[i] = pack_fp8x4(v.x, v.y, v.z, v.w);
}

__global__ __launch_bounds__(256) void convert_w8(const float* __restrict__ Wl,
                                                  const float* __restrict__ Wr,
                                                  unsigned* __restrict__ Wt8) {
  int idx = blockIdx.x * blockDim.x + threadIdx.x;  // NLAYERS*512*HID/4 threads
  int l = idx >> 15;
  int r = idx & 32767;
  int n = r >> 7;
  int k4 = (r & 127) * 4;
  float v[4];
#pragma unroll
  for (int j = 0; j < 4; j++) {
    int k = k4 + j;
    v[j] = (k < 256) ? Wl[(size_t)l * 65536 + k * 256 + n]
                     : Wr[(size_t)l * 65536 + (k - 256) * 256 + n];
  }
  Wt8[idx] = pack_fp8x4(v[0], v[1], v[2], v[3]);
}

// -------------------- FUSED aggregate + fp8 GEMM + BN partials --------------
// Block m0 owns output rows [m0, m0+128). Three phases (acc accumulates across):
//   A: root-half GEMM k=256..511 (h8 + B, double-buffered global_load_lds)
//   B: gather+mean-aggregate the block's 128 nodes -> fp8 into LDS, written in
//      the exact swizzled layout phase C's frag reads expect (write formula ==
//      read formula, self-consistent). aggr8 global round-trip eliminated.
//   C: aggr-half GEMM k=0..255 (A from LDS, zero staging; B double-buffered)
// With 2 blocks/CU, one block's phase-B gather co-schedules with the other's
// MFMA (separate pipes) -- the gather's idle matrix slots get filled.
// LDS (64 KB, time-multiplexed):
//   [0,48K)  phase A: 2 x (As 8K + Bs 16K)
//   [0,32K)  phase B/C: aggr, 4 k-step buffers x [128 rows][64 B swizzled]
//   [32K,64K) phase C: B double-buffer 2 x 16K
//   [32K,40K) epilogue ep8; [40K,44K) bns
__global__ __launch_bounds__(256, 2) void agg_gemm_fused(
    const unsigned char* __restrict__ h8, const int* __restrict__ row_ptr,
    const int* __restrict__ col, const float* __restrict__ inv_cnt,
    const unsigned char* __restrict__ Bt8, unsigned char* __restrict__ hpre8,
    float* __restrict__ psum) {
  __shared__ unsigned char smem[65536];

  int tid = threadIdx.x;
  int wid = tid >> 6, lane = tid & 63;
  int m0 = blockIdx.x * 128;
  int q = lane >> 4, c = lane & 15;
  int wm = (wid >> 1) * 64, wn = (wid & 1) * 128;

  f32x4 zero = {0.f, 0.f, 0.f, 0.f};
  f32x4 acc[4][8];
#pragma unroll
  for (int mi = 0; mi < 4; mi++)
#pragma unroll
    for (int ni = 0; ni < 8; ni++) acc[mi][ni] = zero;

  // staging geometry (16B chunk = 16 fp8 k-elems)
  int srowA0 = wid * 32 + (lane >> 2);
  int cgA0 = (lane & 3) ^ ((srowA0 >> 1) & 3);
  int srowA1 = srowA0 + 16;
  int cgA1 = (lane & 3) ^ ((srowA1 >> 1) & 3);
  int srowB[4], cgB[4];
#pragma unroll
  for (int j = 0; j < 4; j++) {
    srowB[j] = j * 64 + wid * 16 + (lane >> 2);
    cgB[j] = (lane & 3) ^ ((srowB[j] >> 1) & 3);
  }

  // frag-read offsets, relative to a [rows][64B swizzled] tile base
  int aoff[4][2], boff[8][2];
#pragma unroll
  for (int mi = 0; mi < 4; mi++) {
    int row = wm + mi * 16 + c;
    int x = (row >> 1) & 3;
#pragma unroll
    for (int kk = 0; kk < 2; kk++) {
      int chunk = kk * 2 + (q >> 1);
      aoff[mi][kk] = row * 64 + ((chunk ^ x) << 4) + ((q & 1) << 3);
    }
  }
#pragma unroll
  for (int ni = 0; ni < 8; ni++) {
    int row = wn + ni * 16 + c;
    int x = (row >> 1) & 3;
#pragma unroll
    for (int kk = 0; kk < 2; kk++) {
      int chunk = kk * 2 + (q >> 1);
      boff[ni][kk] = row * 64 + ((chunk ^ x) << 4) + ((q & 1) << 3);
    }
  }

  // ---------------- phase A: root half, k0 = 256..448 ----------------
  {
    auto stageA = [&](int k0, int b) {
      unsigned char* As = smem + b * 24576;
      unsigned char* Bs = As + 8192;
      int ksrc = k0 - 256;
      gload16(h8 + ((size_t)(m0 + srowA0) * HID + ksrc + cgA0 * 16),
              &As[(wid * 32) * 64]);
      gload16(h8 + ((size_t)(m0 + srowA1) * HID + ksrc + cgA1 * 16),
              &As[(wid * 32 + 16) * 64]);
#pragma unroll
      for (int j = 0; j < 4; j++)
        gload16(Bt8 + ((size_t)srowB[j] * 512 + k0 + cgB[j] * 16),
                &Bs[(j * 64 + wid * 16) * 64]);
    };
    stageA(256, 0);
    __syncthreads();
#pragma unroll
    for (int t = 0; t < 4; ++t) {
      int cur = t & 1;
      if (t < 3) stageA(256 + (t + 1) * 64, cur ^ 1);
      const unsigned char* As = smem + cur * 24576;
      const unsigned char* Bs = As + 8192;
      long long af[4][2], bfr[8][2];
#pragma unroll
      for (int mi = 0; mi < 4; mi++) {
        af[mi][0] = *(const long long*)&As[aoff[mi][0]];
        af[mi][1] = *(const long long*)&As[aoff[mi][1]];
      }
#pragma unroll
      for (int ni = 0; ni < 8; ni++) {
        bfr[ni][0] = *(const long long*)&Bs[boff[ni][0]];
        bfr[ni][1] = *(const long long*)&Bs[boff[ni][1]];
      }
#pragma unroll
      for (int mi = 0; mi < 4; mi++)
#pragma unroll
        for (int ni = 0; ni < 8; ni++) {
          acc[mi][ni] = __builtin_amdgcn_mfma_f32_16x16x32_fp8_fp8(
              af[mi][0], bfr[ni][0], acc[mi][ni], 0, 0, 0);
          acc[mi][ni] = __builtin_amdgcn_mfma_f32_16x16x32_fp8_fp8(
              af[mi][1], bfr[ni][1], acc[mi][ni], 0, 0, 0);
        }
      __syncthreads();  // also makes phase-A staging region dead below
    }
  }

  // prefetch phase-C's first B tile into [32K,48K) (region now dead; the long
  // gather below hides its latency completely)
  {
    unsigned char* Bs = smem + 32768;
#pragma unroll
    for (int j = 0; j < 4; j++)
      gload16(Bt8 + ((size_t)srowB[j] * 512 + 0 + cgB[j] * 16),
              &Bs[(j * 64 + wid * 16) * 64]);
  }

  // ---------------- phase B: gather + aggregate into LDS ----------------
  {
    int half = lane >> 5, l32 = lane & 31;
    // LDS write slot for this lane (row-dependent part added per node):
    int kstep = l32 >> 3;                 // 0..3
    int chunk = (l32 >> 1) & 3;           // 16B chunk within 64B
    int bytein = (l32 & 1) * 8;
    for (int nloc = 0; nloc < 32; ++nloc) {
      int row = wid * 32 + nloc;          // 0..127
      int node = m0 + row;
      float a[8] = {0.f, 0.f, 0.f, 0.f, 0.f, 0.f, 0.f, 0.f};
      bool valid = (node < N_NODES);
      if (valid) {
        int r0 = row_ptr[node], r1 = row_ptr[node + 1];
        int e = r0 + half;
        for (; e + 14 < r1; e += 16) {
          int s[8];
#pragma unroll
          for (int j = 0; j < 8; j++) s[j] = col[e + 2 * j];
          uint2 v[8];
#pragma unroll
          for (int j = 0; j < 8; j++)
            v[j] = *((const uint2*)(h8 + (size_t)s[j] * HID) + l32);
#pragma unroll
          for (int j = 0; j < 8; j++) { accf8(a, v[j].x); accf8(a + 4, v[j].y); }
        }
        for (; e + 6 < r1; e += 8) {
          int s0 = col[e], s1 = col[e + 2], s2 = col[e + 4], s3 = col[e + 6];
          uint2 v0 = *((const uint2*)(h8 + (size_t)s0 * HID) + l32);
          uint2 v1 = *((const uint2*)(h8 + (size_t)s1 * HID) + l32);
          uint2 v2 = *((const uint2*)(h8 + (size_t)s2 * HID) + l32);
          uint2 v3 = *((const uint2*)(h8 + (size_t)s3 * HID) + l32);
          accf8(a, v0.x); accf8(a + 4, v0.y);
          accf8(a, v1.x); accf8(a + 4, v1.y);
          accf8(a, v2.x); accf8(a + 4, v2.y);
          accf8(a, v3.x); accf8(a + 4, v3.y);
        }
        for (; e < r1; e += 2) {
          int s0 = col[e];
          uint2 v0 = *((const uint2*)(h8 + (size_t)s0 * HID) + l32);
          accf8(a, v0.x); accf8(a + 4, v0.y);
        }
      }
#pragma unroll
      for (int j = 0; j < 8; j++) a[j] += __shfl_xor(a[j], 32, 64);
      if (half == 0) {
        float inv = valid ? inv_cnt[node] : 0.f;
        uint2 o;
        o.x = pack_fp8x4(a[0] * inv, a[1] * inv, a[2] * inv, a[3] * inv);
        o.y = pack_fp8x4(a[4] * inv, a[5] * inv, a[6] * inv, a[7] * inv);
        int chx = chunk ^ ((row >> 1) & 3);
        *(uint2*)(smem + kstep * 8192 + row * 64 + chx * 16 + bytein) = o;
      }
    }
  }
  __syncthreads();  // aggr visible + phase-C B(0) staged (vmcnt drained)

  // ---------------- phase C: aggr half, k0 = 0..192 (A from LDS) -------
  {
    auto stageBC = [&](int k0, int b) {
      unsigned char* Bs = smem + 32768 + b * 16384;
#pragma unroll
      for (int j = 0; j < 4; j++)
        gload16(Bt8 + ((size_t)srowB[j] * 512 + k0 + cgB[j] * 16),
                &Bs[(j * 64 + wid * 16) * 64]);
    };
#pragma unroll
    for (int t = 0; t < 4; ++t) {
      int cur = t & 1;
      if (t < 3) stageBC((t + 1) * 64, cur ^ 1);
      const unsigned char* As = smem + t * 8192;  // aggr k-step t
      const unsigned char* Bs = smem + 32768 + cur * 16384;
      long long af[4][2], bfr[8][2];
#pragma unroll
      for (int mi = 0; mi < 4; mi++) {
        af[mi][0] = *(const long long*)&As[aoff[mi][0]];
        af[mi][1] = *(const long long*)&As[aoff[mi][1]];
      }
#pragma unroll
      for (int ni = 0; ni < 8; ni++) {
        bfr[ni][0] = *(const long long*)&Bs[boff[ni][0]];
        bfr[ni][1] = *(const long long*)&Bs[boff[ni][1]];
      }
#pragma unroll
      for (int mi = 0; mi < 4; mi++)
#pragma unroll
        for (int ni = 0; ni < 8; ni++) {
          acc[mi][ni] = __builtin_amdgcn_mfma_f32_16x16x32_fp8_fp8(
              af[mi][0], bfr[ni][0], acc[mi][ni], 0, 0, 0);
          acc[mi][ni] = __builtin_amdgcn_mfma_f32_16x16x32_fp8_fp8(
              af[mi][1], bfr[ni][1], acc[mi][ni], 0, 0, 0);
        }
      __syncthreads();
    }
  }

  // ---- coalesced fp8 C-store: 4 slabs of 32 rows via LDS transpose ----
  unsigned char* ep8 = smem + 32768;  // 8 KB
  float (*bns)[8][16][2] = (float(*)[8][16][2])(smem + 40960);  // 4 KB
  int rh = wid >> 1;
#pragma unroll
  for (int mi = 0; mi < 4; mi++) {
#pragma unroll
    for (int r = 0; r < 4; r++) {
      int r16 = q * 4 + r;
#pragma unroll
      for (int ni = 0; ni < 8; ni++)
        ep8[(rh * 16 + r16) * 256 + wn + ni * 16 + c] = f2f8(acc[mi][ni][r]);
    }
    __syncthreads();
    int u = tid;
#pragma unroll
    for (int j = 0; j < 2; j++, u += 256) {  // 512 uint4 = 8 KB
      int lr = u >> 4;
      int cu = u & 15;
      int gm = m0 + (lr >> 4) * 64 + mi * 16 + (lr & 15);
      if (gm < N_NODES)
        ((uint4*)(hpre8 + (size_t)gm * HID))[cu] = ((const uint4*)ep8)[u];
    }
    __syncthreads();
  }

  // ---- BN column partials from fp32 acc (mask pad rows) ----
#pragma unroll
  for (int ni = 0; ni < 8; ni++) {
    float s = 0.f, s2 = 0.f;
#pragma unroll
    for (int mi = 0; mi < 4; mi++) {
#pragma unroll
      for (int r = 0; r < 4; r++) {
        int gm = m0 + wm + mi * 16 + q * 4 + r;
        float v = (gm < N_NODES) ? acc[mi][ni][r] : 0.f;
        s += v;
        s2 += v * v;
      }
    }
    s += __shfl_xor(s, 16, 64);
    s += __shfl_xor(s, 32, 64);
    s2 += __shfl_xor(s2, 16, 64);
    s2 += __shfl_xor(s2, 32, 64);
    if (q == 0) {
      bns[wid][ni][c][0] = s;
      bns[wid][ni][c][1] = s2;
    }
  }
  __syncthreads();
  {
    int wnh = tid >> 7, ni = (tid >> 4) & 7, cc = tid & 15;
    float s = bns[wnh][ni][cc][0] + bns[wnh + 2][ni][cc][0];
    float s2 = bns[wnh][ni][cc][1] + bns[wnh + 2][ni][cc][1];
    int coln = wnh * 128 + ni * 16 + cc;
    psum[(size_t)blockIdx.x * 512 + coln] = s;
    psum[(size_t)blockIdx.x * 512 + 256 + coln] = s2;
  }
}

// --------------------------------- BN reduce (tree, atomic-free) ------------
#define BN_MID 16
__global__ __launch_bounds__(256) void bn_mid(const float* __restrict__ psum,
                                              float* __restrict__ tmp) {
  int b = blockIdx.x;
  int f = threadIdx.x;
  int mb0 = b * 49;
  int mb1 = min(mb0 + 49, N_MBLK);
  float s = 0.f, s2 = 0.f;
  for (int mb = mb0; mb < mb1; mb++) {
    s += psum[(size_t)mb * 512 + f];
    s2 += psum[(size_t)mb * 512 + 256 + f];
  }
  tmp[(size_t)b * 512 + f] = s;
  tmp[(size_t)b * 512 + 256 + f] = s2;
}

__global__ void bn_fin(const float* __restrict__ tmp,
                       const float* __restrict__ gamma,
                       const float* __restrict__ beta,
                       float* __restrict__ ss) {
  int f = threadIdx.x;
  float sum = 0.f, sq = 0.f;
#pragma unroll
  for (int b = 0; b < BN_MID; b++) {
    sum += tmp[(size_t)b * 512 + f];
    sq += tmp[(size_t)b * 512 + 256 + f];
  }
  const float invN = 1.0f / (float)N_NODES;
  float mu = sum * invN;
  float ex2 = sq * invN;
  float var = fmaxf(ex2 - mu * mu, 0.f);
  float sc = gamma[f] * rsqrtf(var + 1e-5f);
  ss[f] = sc;
  ss[HID + f] = beta[f] - mu * sc;
}

// BN+ReLU apply: fp8 hpre -> fp8 h.
__global__ __launch_bounds__(256) void bn_apply_h8(const uint2* __restrict__ hpre8,
                                                   const float* __restrict__ ss,
                                                   uint2* __restrict__ h8out) {
  int idx0 = blockIdx.x * blockDim.x + threadIdx.x;
  int cb = (idx0 & 31) * 8;  // column base (row = 32 uint2)
  float sc[8], sh[8];
#pragma unroll
  for (int j = 0; j < 8; j++) { sc[j] = ss[cb + j]; sh[j] = ss[HID + cb + j]; }
  const int total = N_NODES * 32;
  const int step = gridDim.x * blockDim.x;  // 524288, multiple of 32
  for (int i = idx0; i < total; i += step) {
    uint2 v = hpre8[i];
    float f[8];
    decf8(f, v.x);
    decf8(f + 4, v.y);
#pragma unroll
    for (int j = 0; j < 8; j++)
      f[j] = fmaxf(fmaf(f[j], sc[j], sh[j]), 0.f);
    uint2 o;
    o.x = pack_fp8x4(f[0], f[1], f[2], f[3]);
    o.y = pack_fp8x4(f[4], f[5], f[6], f[7]);
    h8out[i] = o;
  }
}

// ---------------- pool stage 1: per-(graph, chunk) BN+ReLU partial sums -----
__global__ __launch_bounds__(256) void pool_partial(
    const unsigned char* __restrict__ hpre8, const float* __restrict__ ss,
    const int* __restrict__ batch, float* __restrict__ partial) {
  __shared__ float red[256][9];
  int g = blockIdx.x;
  int i = blockIdx.y;
  int t = threadIdx.x;
  int a = 0, b = N_NODES;
  while (a < b) { int m = (a + b) >> 1; if (batch[m] < g) a = m + 1; else b = m; }
  int lo = a;
  b = N_NODES;
  while (a < b) { int m = (a + b) >> 1; if (batch[m] < g + 1) a = m + 1; else b = m; }
  int hi = a;
  int len = hi - lo;
  int clen = (len + 7) >> 3;
  int c0 = lo + i * clen;
  int c1 = min(c0 + clen, hi);

  int rs = t >> 5, cu = t & 31;
  int cb = cu * 8;
  float scv[8], shv[8];
#pragma unroll
  for (int j = 0; j < 8; j++) { scv[j] = ss[cb + j]; shv[j] = ss[HID + cb + j]; }
  float acc[8] = {0.f, 0.f, 0.f, 0.f, 0.f, 0.f, 0.f, 0.f};
  for (int r = c0 + rs; r < c1; r += 8) {
    uint2 v = *((const uint2*)(hpre8 + (size_t)r * HID) + cu);
    float f[8];
    decf8(f, v.x);
    decf8(f + 4, v.y);
#pragma unroll
    for (int j = 0; j < 8; j++)
      acc[j] += fmaxf(fmaf(f[j], scv[j], shv[j]), 0.f);
  }
#pragma unroll
  for (int j = 0; j < 8; j++) red[t][j] = acc[j];
  __syncthreads();
  int cc = t >> 3, j = t & 7;
  float sum = 0.f;
#pragma unroll
  for (int k = 0; k < 8; k++) sum += red[k * 32 + cc][j];
  partial[((size_t)g * 8 + i) * 256 + t] = sum;
}

// ---------------- pool stage 2 + MLP (64 blocks, reads 8 partials/graph) ----
__global__ __launch_bounds__(256) void pool_mlp_final(
    const float* __restrict__ partial, const int* __restrict__ batch,
    const float* __restrict__ W1, const float* __restrict__ b1,
    const float* __restrict__ W2, const float* __restrict__ b2,
    float* __restrict__ out) {
  __shared__ float gs[HID];
  __shared__ float ts[HID];
  __shared__ float rn[PROJ];
  int g = blockIdx.x;
  int t = threadIdx.x;
  int a = 0, b = N_NODES;
  while (a < b) { int m = (a + b) >> 1; if (batch[m] < g) a = m + 1; else b = m; }
  int lo = a;
  b = N_NODES;
  while (a < b) { int m = (a + b) >> 1; if (batch[m] < g + 1) a = m + 1; else b = m; }
  int len = a - lo;

  float sum = 0.f;
#pragma unroll
  for (int i = 0; i < 8; i++) sum += partial[((size_t)g * 8 + i) * 256 + t];
  float inv = 1.0f / fmaxf((float)len, 1.0f);
  gs[t] = sum * inv;
  __syncthreads();

  float s = b1[t];
  for (int k = 0; k < HID; k++) s = fmaf(gs[k], W1[(size_t)k * HID + t], s);
  ts[t] = fmaxf(s, 0.f);
  __syncthreads();
  float z = 0.f;
  if (t < PROJ) {
    z = b2[t];
    for (int k = 0; k < HID; k++) z = fmaf(ts[k], W2[(size_t)k * PROJ + t], z);
    rn[t] = z * z;
  }
  __syncthreads();
  for (int off = PROJ / 2; off > 0; off >>= 1) {
    if (t < off) rn[t] += rn[t + off];
    __syncthreads();
  }
  float norm = fmaxf(sqrtf(rn[0]), 1e-12f);
  if (t < PROJ) out[(size_t)g * PROJ + t] = z / norm;
}

// --------------------------------------------------------------- launch -----
extern "C" void kernel_launch(void* const* d_in, const int* in_sizes, int n_in,
                              void* d_out, int out_size, void* d_ws, size_t ws_size,
                              hipStream_t stream) {
  const float* x = (const float*)d_in[0];
  const int* ei = (const int*)d_in[1];
  const int* src = ei;
  const int* dst = ei + N_EDGES;
  const int* batch = (const int*)d_in[2];
  const float* Wl = (const float*)d_in[3];
  // d_in[4] = bl: per-column bias is exactly cancelled by BatchNorm -> unused
  const float* Wr = (const float*)d_in[5];
  const float* gamma = (const float*)d_in[6];
  const float* beta = (const float*)d_in[7];
  const float* W1 = (const float*)d_in[8];
  const float* b1 = (const float*)d_in[9];
  const float* W2 = (const float*)d_in[10];
  const float* b2 = (const float*)d_in[11];
  float* out = (float*)d_out;

  char* p = (char*)d_ws;
  const size_t H8 = (size_t)M_PAD * HID;                 // 25.6 MB
  unsigned char* hpre8 = (unsigned char*)p; p += H8;     // fp8 pre-BN activations
  unsigned char* h8 = (unsigned char*)p;    p += H8;
  unsigned char* Wt8 = (unsigned char*)p;   p += (size_t)NLAYERS * 512 * HID;  // 0.5 MB
  int* col = (int*)p;    p += (size_t)N_EDGES * sizeof(int);              // 6.4 MB
  int* row_ptr = (int*)p; p += 400016;
  float* inv_cnt = (float*)p; p += (size_t)N_NODES * sizeof(float);
  float* psum = (float*)p;    p += (size_t)N_MBLK * 512 * sizeof(float);  // 1.6 MB
  float* tmp = (float*)p;     p += (size_t)BN_MID * 512 * sizeof(float);
  float* ss = (float*)p;      p += 512 * sizeof(float);
  float* partial = (float*)p; p += (size_t)N_GRAPHS * 8 * 256 * sizeof(float);
  uint2* ebuf = (uint2*)p;    p += (size_t)N_BUCKETS * EBUF_STRIDE * sizeof(uint2);  // 25.6 MB

  // transient CSR-build arrays overlaid into hpre8 (first written in layer-0
  // fused kernel, which is stream-ordered after csr_build completes)
  u64* bfill64 = (u64*)hpre8;                      // N_BUCKETS lines (padded x8)
  int* bucket_base = (int*)(bfill64 + (size_t)N_BUCKETS * 8);

  // ---- build CSR (once; edge_index is layer-invariant) ----
  hipMemsetAsync(bfill64, 0, (size_t)N_BUCKETS * 8 * sizeof(u64), stream);
  bucket_scatter<<<CSR_NBLK, CSR_BLK, 0, stream>>>(src, dst, bfill64, ebuf);
  bucket_prefix<<<1, 512, 0, stream>>>(bfill64, bucket_base, row_ptr);
  csr_build<<<N_BUCKETS, CSR_BLK, 0, stream>>>(ebuf, bfill64, bucket_base,
                                               row_ptr, inv_cnt, col);

  // ---- one-time converts ----
  convert_x8<<<N_NODES / 4, 256, 0, stream>>>((const float4*)x, (unsigned*)h8);
  convert_w8<<<(NLAYERS * 512 * HID / 4) / 256, 256, 0, stream>>>(Wl, Wr,
                                                                  (unsigned*)Wt8);

  for (int l = 0; l < NLAYERS; l++) {
    agg_gemm_fused<<<N_MBLK, 256, 0, stream>>>(h8, row_ptr, col, inv_cnt,
                                               Wt8 + (size_t)l * 512 * HID,
                                               hpre8, psum);
    bn_mid<<<BN_MID, 256, 0, stream>>>(psum, tmp);
    bn_fin<<<1, 256, 0, stream>>>(tmp, gamma + (size_t)l * HID,
                                  beta + (size_t)l * HID, ss);
    if (l < NLAYERS - 1) {
      bn_apply_h8<<<2048, 256, 0, stream>>>((const uint2*)hpre8, ss, (uint2*)h8);
    }
  }

  // layer-3 BN+ReLU fused into two-stage pooling (reads hpre8 + ss)
  pool_partial<<<dim3(N_GRAPHS, 8), 256, 0, stream>>>(hpre8, ss, batch, partial);
  pool_mlp_final<<<N_GRAPHS, 256, 0, stream>>>(partial, batch, W1, b1, W2, b2, out);
}

// Round 9
// 769.347 us; speedup vs baseline: 1.5647x; 1.5647x over previous
//
#include <hip/hip_runtime.h>

#define N_NODES 100000
#define M_PAD   100096   // 782 * 128
#define N_MBLK  782
#define N_EDGES 1600000
#define N_GRAPHS 64
#define HID 256
#define PROJ 128
#define NLAYERS 4

#define EBUF_STRIDE 8192
#define N_BUCKETS ((N_NODES + 255) / 256)  // 391
#define CSR_BLK 1024
#define EPT 10
#define CSR_NBLK ((N_EDGES + CSR_BLK * EPT - 1) / (CSR_BLK * EPT))  // 157
#define SENT 0xFFFFFFFFu
#define GEMM_BUF 24576  // one LDS buffer: A 128x64 + B 256x64 fp8

typedef unsigned short u16;
typedef unsigned long long u64;
typedef __attribute__((ext_vector_type(4))) float f32x4;
typedef __attribute__((ext_vector_type(2))) float vf2;

__device__ __forceinline__ void gload16(const void* g, void* l) {
  __builtin_amdgcn_global_load_lds((const __attribute__((address_space(1))) void*)g,
                                   (__attribute__((address_space(3))) void*)l, 16, 0, 0);
}
// ---- fp8 e4m3 (HW cvt; encode/decode self-consistent) ----
__device__ __forceinline__ unsigned pack_fp8x4(float a, float b, float c, float d) {
  int v = __builtin_amdgcn_cvt_pk_fp8_f32(a, b, 0, false);
  v = __builtin_amdgcn_cvt_pk_fp8_f32(c, d, v, true);
  return (unsigned)v;
}
__device__ __forceinline__ unsigned char f2f8(float a) {
  return (unsigned char)(__builtin_amdgcn_cvt_pk_fp8_f32(a, a, 0, false) & 0xFF);
}
__device__ __forceinline__ void accf8(float* a, unsigned w) {
  vf2 lo = __builtin_amdgcn_cvt_pk_f32_fp8((int)w, false);
  vf2 hi = __builtin_amdgcn_cvt_pk_f32_fp8((int)w, true);
  a[0] += lo.x; a[1] += lo.y; a[2] += hi.x; a[3] += hi.y;
}
__device__ __forceinline__ void decf8(float* f, unsigned w) {
  vf2 lo = __builtin_amdgcn_cvt_pk_f32_fp8((int)w, false);
  vf2 hi = __builtin_amdgcn_cvt_pk_f32_fp8((int)w, true);
  f[0] = lo.x; f[1] = lo.y; f[2] = hi.x; f[3] = hi.y;
}

// ---------------------------------------------------------------- CSR -------
__global__ __launch_bounds__(1024) void bucket_scatter(
    const int* __restrict__ src, const int* __restrict__ dst,
    u64* __restrict__ bfill64, uint2* __restrict__ ebuf) {
  __shared__ int lhist[N_BUCKETS];
  __shared__ int lbase[N_BUCKETS];
  int t = threadIdx.x;
  int e0 = blockIdx.x * (CSR_BLK * EPT) + t;
  for (int i = t; i < N_BUCKETS; i += CSR_BLK) lhist[i] = 0;
  __syncthreads();
  int sv[EPT], dv[EPT];
#pragma unroll
  for (int j = 0; j < EPT; j++) {
    int e = e0 + j * CSR_BLK;
    if (e < N_EDGES) {
      sv[j] = src[e];
      dv[j] = dst[e];
      atomicAdd(&lhist[dv[j] >> 8], 1);
    } else {
      dv[j] = -1;
      sv[j] = 0;
    }
  }
  __syncthreads();
  for (int i = t; i < N_BUCKETS; i += CSR_BLK) {
    int c = lhist[i];
    if (c > 0) {
      int rounded = (c + 7) & ~7;  // 8 slots = 64B line alignment
      u64 old = atomicAdd(&bfill64[(size_t)i * 8],
                          ((u64)rounded << 32) | (u64)c);
      int base = (int)(old >> 32);
      lbase[i] = base;
      for (int k = c; k < rounded; k++) {  // self-write pad sentinels
        int p = base + k;
        if (p < EBUF_STRIDE) {
          uint2 q; q.x = 0; q.y = SENT;
          ebuf[(size_t)i * EBUF_STRIDE + p] = q;
        }
      }
      lhist[i] = 0;  // reuse as block-local fill cursor
    }
  }
  __syncthreads();
#pragma unroll
  for (int j = 0; j < EPT; j++) {
    if (dv[j] >= 0) {
      int b = dv[j] >> 8;
      int p = lbase[b] + atomicAdd(&lhist[b], 1);
      if (p < EBUF_STRIDE) {  // ~47-sigma margin; drop-safe guard
        uint2 q;
        q.x = (unsigned)sv[j];
        q.y = (unsigned)dv[j];
        ebuf[(size_t)b * EBUF_STRIDE + p] = q;
      }
    }
  }
}

__global__ __launch_bounds__(512) void bucket_prefix(
    const u64* __restrict__ bfill64, int* __restrict__ bucket_base,
    int* __restrict__ row_ptr) {
  __shared__ int tile[512];
  int t = threadIdx.x;
  int v = 0;
  if (t < N_BUCKETS) {
    u64 w = bfill64[(size_t)t * 8];
    v = (int)(w & 0xFFFFFFFFull);
    if ((int)(w >> 32) > EBUF_STRIDE) v = min(v, EBUF_STRIDE);  // degenerate clamp
  }
  tile[t] = v;
  __syncthreads();
  for (int off = 1; off < 512; off <<= 1) {
    int add = (t >= off) ? tile[t - off] : 0;
    __syncthreads();
    tile[t] += add;
    __syncthreads();
  }
  if (t < N_BUCKETS) bucket_base[t] = tile[t] - v;  // exclusive
  if (t == N_BUCKETS - 1) row_ptr[N_NODES] = tile[t];
}

__global__ __launch_bounds__(1024) void csr_build(
    const uint2* __restrict__ ebuf, const u64* __restrict__ bfill64,
    const int* __restrict__ bucket_base, int* __restrict__ row_ptr,
    float* __restrict__ inv_cnt, int* __restrict__ col) {
  __shared__ int hist[256];
  __shared__ int nscan[256];
  __shared__ int cursor[256];
  int b = blockIdx.x;
  int t = threadIdx.x;
  int nalloc = min((int)(bfill64[(size_t)b * 8] >> 32), EBUF_STRIDE);
  int bbase = bucket_base[b];
  if (t < 256) hist[t] = 0;
  __syncthreads();
  uint2 q[8];
#pragma unroll
  for (int k = 0; k < 8; k++) {
    int i = t + k * CSR_BLK;
    q[k].x = 0; q[k].y = SENT;
    if (i < nalloc) {
      q[k] = ebuf[(size_t)b * EBUF_STRIDE + i];
      if (q[k].y != SENT) atomicAdd(&hist[q[k].y & 255], 1);
    }
  }
  __syncthreads();
  if (t < 256) nscan[t] = hist[t];
  __syncthreads();
  for (int off = 1; off < 256; off <<= 1) {
    int add = 0;
    if (t < 256 && t >= off) add = nscan[t - off];
    __syncthreads();
    if (t < 256) nscan[t] += add;
    __syncthreads();
  }
  int nb = min(256, N_NODES - b * 256);
  if (t < 256) {
    int excl = nscan[t] - hist[t];
    cursor[t] = excl;
    if (t < nb) {
      row_ptr[b * 256 + t] = bbase + excl;
      inv_cnt[b * 256 + t] = 1.0f / fmaxf((float)hist[t], 1.0f);
    }
  }
  __syncthreads();
#pragma unroll
  for (int k = 0; k < 8; k++) {
    if (q[k].y != SENT) {
      int l = (int)(q[k].y & 255);
      int pos = bbase + atomicAdd(&cursor[l], 1);
      col[pos] = (int)q[k].x;
    }
  }
}

// ------------------------------------------------------------ converts ------
__global__ __launch_bounds__(256) void convert_x8(const float4* __restrict__ x,
                                                  unsigned* __restrict__ h8) {
  int i = blockIdx.x * blockDim.x + threadIdx.x;  // exactly N_NODES*64 threads
  float4 v = x[i];
  h8[i] = pack_fp8x4(v.x, v.y, v.z, v.w);
}

__global__ __launch_bounds__(256) void convert_w8(const float* __restrict__ Wl,
                                                  const float* __restrict__ Wr,
                                                  unsigned* __restrict__ Wt8) {
  int idx = blockIdx.x * blockDim.x + threadIdx.x;  // NLAYERS*512*HID/4 threads
  int l = idx >> 15;
  int r = idx & 32767;
  int n = r >> 7;
  int k4 = (r & 127) * 4;
  float v[4];
#pragma unroll
  for (int j = 0; j < 4; j++) {
    int k = k4 + j;
    v[j] = (k < 256) ? Wl[(size_t)l * 65536 + k * 256 + n]
                     : Wr[(size_t)l * 65536 + (k - 256) * 256 + n];
  }
  Wt8[idx] = pack_fp8x4(v[0], v[1], v[2], v[3]);
}

// ----------------------------------------------------------- aggregation ----
// one wave per node; 25000 blocks for max TLP (the gather is latency-bound and
// needs wave count -- round-8's fusion proved this: 17% occupancy => 3x slower).
__global__ __launch_bounds__(256) void aggregate_fp8(
    const unsigned char* __restrict__ h8, const int* __restrict__ row_ptr,
    const int* __restrict__ col, const float* __restrict__ inv_cnt,
    unsigned char* __restrict__ aggr8) {
  int node = blockIdx.x * 4 + (threadIdx.x >> 6);
  int lane = threadIdx.x & 63;
  int half = lane >> 5, l32 = lane & 31;
  int r0 = row_ptr[node], r1 = row_ptr[node + 1];
  float a[8] = {0.f, 0.f, 0.f, 0.f, 0.f, 0.f, 0.f, 0.f};
  int e = r0 + half;
  for (; e + 14 < r1; e += 16) {
    int s[8];
#pragma unroll
    for (int j = 0; j < 8; j++) s[j] = col[e + 2 * j];
    uint2 v[8];
#pragma unroll
    for (int j = 0; j < 8; j++)
      v[j] = *((const uint2*)(h8 + (size_t)s[j] * HID) + l32);
#pragma unroll
    for (int j = 0; j < 8; j++) { accf8(a, v[j].x); accf8(a + 4, v[j].y); }
  }
  for (; e + 6 < r1; e += 8) {
    int s0 = col[e], s1 = col[e + 2], s2 = col[e + 4], s3 = col[e + 6];
    uint2 v0 = *((const uint2*)(h8 + (size_t)s0 * HID) + l32);
    uint2 v1 = *((const uint2*)(h8 + (size_t)s1 * HID) + l32);
    uint2 v2 = *((const uint2*)(h8 + (size_t)s2 * HID) + l32);
    uint2 v3 = *((const uint2*)(h8 + (size_t)s3 * HID) + l32);
    accf8(a, v0.x); accf8(a + 4, v0.y);
    accf8(a, v1.x); accf8(a + 4, v1.y);
    accf8(a, v2.x); accf8(a + 4, v2.y);
    accf8(a, v3.x); accf8(a + 4, v3.y);
  }
  for (; e < r1; e += 2) {
    int s0 = col[e];
    uint2 v0 = *((const uint2*)(h8 + (size_t)s0 * HID) + l32);
    accf8(a, v0.x); accf8(a + 4, v0.y);
  }
#pragma unroll
  for (int j = 0; j < 8; j++) a[j] += __shfl_xor(a[j], 32, 64);
  if (half == 0) {
    float inv = inv_cnt[node];
    uint2 o;
    o.x = pack_fp8x4(a[0] * inv, a[1] * inv, a[2] * inv, a[3] * inv);
    o.y = pack_fp8x4(a[4] * inv, a[5] * inv, a[6] * inv, a[7] * inv);
    *((uint2*)(aggr8 + (size_t)node * HID) + l32) = o;
  }
}

// ------------------------------- fp8 MFMA GEMM + fused BN partials ----------
// hpre8[m][n] = fp8(sum_k cat(aggr8,h8)[m][k] * B[k][n]);  B^T given as Wt8[n][k].
// 128x256 tile, BK=64 fp8. T4 COUNTED-VMCNT pipeline (2-deep prefetch):
// round-5's dbuf failed because __syncthreads drains vmcnt(0) -- the prefetch
// was waited on at the same iteration's barrier. Here: raw s_barrier + explicit
// s_waitcnt vmcnt(6) keeps the NEXT tile's 6 loads in flight across the
// barrier. Per-wave vmcnt(6) of 12 outstanding == oldest tile's 6 landed;
// barrier makes that true for all waves => tile complete.
__global__ __launch_bounds__(256, 2) void gemm_fused_fp8(
    const unsigned char* __restrict__ a8, const unsigned char* __restrict__ h8,
    const unsigned char* __restrict__ Bt8, unsigned char* __restrict__ hpre8,
    float* __restrict__ psum) {
  __shared__ unsigned char smem[2 * GEMM_BUF];  // 48 KB (2 x (A 8K + B 16K))
  __shared__ float bns[4][8][16][2];            // 4 KB

  int tid = threadIdx.x;
  int wid = tid >> 6, lane = tid & 63;
  int m0 = blockIdx.x * 128;
  int q = lane >> 4, c = lane & 15;
  int wm = (wid >> 1) * 64, wn = (wid & 1) * 128;

  f32x4 zero = {0.f, 0.f, 0.f, 0.f};
  f32x4 acc[4][8];
#pragma unroll
  for (int mi = 0; mi < 4; mi++)
#pragma unroll
    for (int ni = 0; ni < 8; ni++) acc[mi][ni] = zero;

  // A staging geometry (2 issues/thread); 16B chunk = 16 fp8 k-elems
  int srowA0 = wid * 32 + (lane >> 2);
  int cgA0 = (lane & 3) ^ ((srowA0 >> 1) & 3);
  int srowA1 = srowA0 + 16;
  int cgA1 = (lane & 3) ^ ((srowA1 >> 1) & 3);
  // B staging geometry (4 issues/thread)
  int srowB[4], cgB[4];
#pragma unroll
  for (int j = 0; j < 4; j++) {
    srowB[j] = j * 64 + wid * 16 + (lane >> 2);
    cgB[j] = (lane & 3) ^ ((srowB[j] >> 1) & 3);
  }

  // frag-read LDS byte offsets: per mi/ni and per kk (K=32 half of BK=64)
  int aoff[4][2], boff[8][2];
#pragma unroll
  for (int mi = 0; mi < 4; mi++) {
    int row = wm + mi * 16 + c;
    int x = (row >> 1) & 3;
#pragma unroll
    for (int kk = 0; kk < 2; kk++) {
      int chunk = kk * 2 + (q >> 1);
      aoff[mi][kk] = row * 64 + ((chunk ^ x) << 4) + ((q & 1) << 3);
    }
  }
#pragma unroll
  for (int ni = 0; ni < 8; ni++) {
    int row = wn + ni * 16 + c;
    int x = (row >> 1) & 3;
#pragma unroll
    for (int kk = 0; kk < 2; kk++) {
      int chunk = kk * 2 + (q >> 1);
      boff[ni][kk] = row * 64 + ((chunk ^ x) << 4) + ((q & 1) << 3);
    }
  }

  auto stage = [&](int k0, int b) {  // 6 global_load_lds per thread
    const unsigned char* Asrc = (k0 < 256) ? a8 : h8;
    int ksrc = k0 & 255;
    unsigned char* As = smem + b * GEMM_BUF;
    unsigned char* Bs = As + 128 * 64;
    gload16(Asrc + ((size_t)(m0 + srowA0) * HID + ksrc + cgA0 * 16),
            &As[(wid * 32) * 64]);
    gload16(Asrc + ((size_t)(m0 + srowA1) * HID + ksrc + cgA1 * 16),
            &As[(wid * 32 + 16) * 64]);
#pragma unroll
    for (int j = 0; j < 4; j++)
      gload16(Bt8 + ((size_t)srowB[j] * 512 + k0 + cgB[j] * 16),
              &Bs[(j * 64 + wid * 16) * 64]);
  };

  // 2-deep prologue: tiles 0 and 1 in flight (12 outstanding per wave)
  stage(0, 0);
  stage(64, 1);
#pragma unroll
  for (int t = 0; t < 8; ++t) {
    int cur = t & 1;
    // wait for tile t's 6 loads (the older half of 12); keep tile t+1 in flight
    if (t < 7) {
      asm volatile("s_waitcnt vmcnt(6)" ::: "memory");
    } else {
      asm volatile("s_waitcnt vmcnt(0)" ::: "memory");
    }
    __builtin_amdgcn_sched_barrier(0);
    __builtin_amdgcn_s_barrier();  // raw: does NOT drain the in-flight tile
    const unsigned char* As = smem + cur * GEMM_BUF;
    const unsigned char* Bs = As + 128 * 64;
    long long af[4][2], bfr[8][2];
#pragma unroll
    for (int mi = 0; mi < 4; mi++) {
      af[mi][0] = *(const long long*)&As[aoff[mi][0]];
      af[mi][1] = *(const long long*)&As[aoff[mi][1]];
    }
#pragma unroll
    for (int ni = 0; ni < 8; ni++) {
      bfr[ni][0] = *(const long long*)&Bs[boff[ni][0]];
      bfr[ni][1] = *(const long long*)&Bs[boff[ni][1]];
    }
#pragma unroll
    for (int mi = 0; mi < 4; mi++)
#pragma unroll
      for (int ni = 0; ni < 8; ni++) {
        acc[mi][ni] = __builtin_amdgcn_mfma_f32_16x16x32_fp8_fp8(
            af[mi][0], bfr[ni][0], acc[mi][ni], 0, 0, 0);
        acc[mi][ni] = __builtin_amdgcn_mfma_f32_16x16x32_fp8_fp8(
            af[mi][1], bfr[ni][1], acc[mi][ni], 0, 0, 0);
      }
    __builtin_amdgcn_s_barrier();  // all waves done reading buf[cur]
    if (t < 6) stage((t + 2) * 64, cur);  // refill the buffer just consumed
  }

  // ---- coalesced fp8 C-store: 4 slabs of 32 rows via LDS transpose ----
  unsigned char* ep8 = smem;  // 32 x 256 fp8 = 8 KB
  int rh = wid >> 1;  // row half (0: rows 0-63, 1: rows 64-127)
#pragma unroll
  for (int mi = 0; mi < 4; mi++) {
#pragma unroll
    for (int r = 0; r < 4; r++) {
      int r16 = q * 4 + r;
#pragma unroll
      for (int ni = 0; ni < 8; ni++)
        ep8[(rh * 16 + r16) * 256 + wn + ni * 16 + c] = f2f8(acc[mi][ni][r]);
    }
    __syncthreads();
    int u = tid;
#pragma unroll
    for (int j = 0; j < 2; j++, u += 256) {  // 512 uint4 = 8 KB
      int lr = u >> 4;     // 0..31 local row
      int cu = u & 15;     // uint4 column (16 B = 16 cols)
      int gm = m0 + (lr >> 4) * 64 + mi * 16 + (lr & 15);
      if (gm < N_NODES)
        ((uint4*)(hpre8 + (size_t)gm * HID))[cu] = ((const uint4*)ep8)[u];
    }
    __syncthreads();
  }

  // ---- BN column partials from fp32 acc (mask pad rows) ----
#pragma unroll
  for (int ni = 0; ni < 8; ni++) {
    float s = 0.f, s2 = 0.f;
#pragma unroll
    for (int mi = 0; mi < 4; mi++) {
#pragma unroll
      for (int r = 0; r < 4; r++) {
        int gm = m0 + wm + mi * 16 + q * 4 + r;
        float v = (gm < N_NODES) ? acc[mi][ni][r] : 0.f;
        s += v;
        s2 += v * v;
      }
    }
    s += __shfl_xor(s, 16, 64);
    s += __shfl_xor(s, 32, 64);
    s2 += __shfl_xor(s2, 16, 64);
    s2 += __shfl_xor(s2, 32, 64);
    if (q == 0) {
      bns[wid][ni][c][0] = s;
      bns[wid][ni][c][1] = s2;
    }
  }
  __syncthreads();
  {
    int wnh = tid >> 7, ni = (tid >> 4) & 7, cc = tid & 15;
    float s = bns[wnh][ni][cc][0] + bns[wnh + 2][ni][cc][0];
    float s2 = bns[wnh][ni][cc][1] + bns[wnh + 2][ni][cc][1];
    int coln = wnh * 128 + ni * 16 + cc;
    psum[(size_t)blockIdx.x * 512 + coln] = s;
    psum[(size_t)blockIdx.x * 512 + 256 + coln] = s2;
  }
}

// --------------------------------- BN reduce (tree, atomic-free) ------------
#define BN_MID 16
__global__ __launch_bounds__(256) void bn_mid(const float* __restrict__ psum,
                                              float* __restrict__ tmp) {
  int b = blockIdx.x;
  int f = threadIdx.x;
  int mb0 = b * 49;
  int mb1 = min(mb0 + 49, N_MBLK);
  float s = 0.f, s2 = 0.f;
  for (int mb = mb0; mb < mb1; mb++) {
    s += psum[(size_t)mb * 512 + f];
    s2 += psum[(size_t)mb * 512 + 256 + f];
  }
  tmp[(size_t)b * 512 + f] = s;
  tmp[(size_t)b * 512 + 256 + f] = s2;
}

__global__ void bn_fin(const float* __restrict__ tmp,
                       const float* __restrict__ gamma,
                       const float* __restrict__ beta,
                       float* __restrict__ ss) {
  int f = threadIdx.x;
  float sum = 0.f, sq = 0.f;
#pragma unroll
  for (int b = 0; b < BN_MID; b++) {
    sum += tmp[(size_t)b * 512 + f];
    sq += tmp[(size_t)b * 512 + 256 + f];
  }
  const float invN = 1.0f / (float)N_NODES;
  float mu = sum * invN;
  float ex2 = sq * invN;
  float var = fmaxf(ex2 - mu * mu, 0.f);
  float sc = gamma[f] * rsqrtf(var + 1e-5f);
  ss[f] = sc;
  ss[HID + f] = beta[f] - mu * sc;
}

// BN+ReLU apply: fp8 hpre -> fp8 h.
__global__ __launch_bounds__(256) void bn_apply_h8(const uint2* __restrict__ hpre8,
                                                   const float* __restrict__ ss,
                                                   uint2* __restrict__ h8out) {
  int idx0 = blockIdx.x * blockDim.x + threadIdx.x;
  int cb = (idx0 & 31) * 8;  // column base (row = 32 uint2)
  float sc[8], sh[8];
#pragma unroll
  for (int j = 0; j < 8; j++) { sc[j] = ss[cb + j]; sh[j] = ss[HID + cb + j]; }
  const int total = N_NODES * 32;
  const int step = gridDim.x * blockDim.x;  // 524288, multiple of 32
  for (int i = idx0; i < total; i += step) {
    uint2 v = hpre8[i];
    float f[8];
    decf8(f, v.x);
    decf8(f + 4, v.y);
#pragma unroll
    for (int j = 0; j < 8; j++)
      f[j] = fmaxf(fmaf(f[j], sc[j], sh[j]), 0.f);
    uint2 o;
    o.x = pack_fp8x4(f[0], f[1], f[2], f[3]);
    o.y = pack_fp8x4(f[4], f[5], f[6], f[7]);
    h8out[i] = o;
  }
}

// ---------------- pool stage 1: per-(graph, chunk) BN+ReLU partial sums -----
__global__ __launch_bounds__(256) void pool_partial(
    const unsigned char* __restrict__ hpre8, const float* __restrict__ ss,
    const int* __restrict__ batch, float* __restrict__ partial) {
  __shared__ float red[256][9];
  int g = blockIdx.x;
  int i = blockIdx.y;
  int t = threadIdx.x;
  int a = 0, b = N_NODES;
  while (a < b) { int m = (a + b) >> 1; if (batch[m] < g) a = m + 1; else b = m; }
  int lo = a;
  b = N_NODES;
  while (a < b) { int m = (a + b) >> 1; if (batch[m] < g + 1) a = m + 1; else b = m; }
  int hi = a;
  int len = hi - lo;
  int clen = (len + 7) >> 3;
  int c0 = lo + i * clen;
  int c1 = min(c0 + clen, hi);

  int rs = t >> 5, cu = t & 31;
  int cb = cu * 8;
  float scv[8], shv[8];
#pragma unroll
  for (int j = 0; j < 8; j++) { scv[j] = ss[cb + j]; shv[j] = ss[HID + cb + j]; }
  float acc[8] = {0.f, 0.f, 0.f, 0.f, 0.f, 0.f, 0.f, 0.f};
  for (int r = c0 + rs; r < c1; r += 8) {
    uint2 v = *((const uint2*)(hpre8 + (size_t)r * HID) + cu);
    float f[8];
    decf8(f, v.x);
    decf8(f + 4, v.y);
#pragma unroll
    for (int j = 0; j < 8; j++)
      acc[j] += fmaxf(fmaf(f[j], scv[j], shv[j]), 0.f);
  }
#pragma unroll
  for (int j = 0; j < 8; j++) red[t][j] = acc[j];
  __syncthreads();
  int cc = t >> 3, j = t & 7;
  float sum = 0.f;
#pragma unroll
  for (int k = 0; k < 8; k++) sum += red[k * 32 + cc][j];
  partial[((size_t)g * 8 + i) * 256 + t] = sum;
}

// ---------------- pool stage 2 + MLP (64 blocks, reads 8 partials/graph) ----
__global__ __launch_bounds__(256) void pool_mlp_final(
    const float* __restrict__ partial, const int* __restrict__ batch,
    const float* __restrict__ W1, const float* __restrict__ b1,
    const float* __restrict__ W2, const float* __restrict__ b2,
    float* __restrict__ out) {
  __shared__ float gs[HID];
  __shared__ float ts[HID];
  __shared__ float rn[PROJ];
  int g = blockIdx.x;
  int t = threadIdx.x;
  int a = 0, b = N_NODES;
  while (a < b) { int m = (a + b) >> 1; if (batch[m] < g) a = m + 1; else b = m; }
  int lo = a;
  b = N_NODES;
  while (a < b) { int m = (a + b) >> 1; if (batch[m] < g + 1) a = m + 1; else b = m; }
  int len = a - lo;

  float sum = 0.f;
#pragma unroll
  for (int i = 0; i < 8; i++) sum += partial[((size_t)g * 8 + i) * 256 + t];
  float inv = 1.0f / fmaxf((float)len, 1.0f);
  gs[t] = sum * inv;
  __syncthreads();

  float s = b1[t];
  for (int k = 0; k < HID; k++) s = fmaf(gs[k], W1[(size_t)k * HID + t], s);
  ts[t] = fmaxf(s, 0.f);
  __syncthreads();
  float z = 0.f;
  if (t < PROJ) {
    z = b2[t];
    for (int k = 0; k < HID; k++) z = fmaf(ts[k], W2[(size_t)k * PROJ + t], z);
    rn[t] = z * z;
  }
  __syncthreads();
  for (int off = PROJ / 2; off > 0; off >>= 1) {
    if (t < off) rn[t] += rn[t + off];
    __syncthreads();
  }
  float norm = fmaxf(sqrtf(rn[0]), 1e-12f);
  if (t < PROJ) out[(size_t)g * PROJ + t] = z / norm;
}

// --------------------------------------------------------------- launch -----
extern "C" void kernel_launch(void* const* d_in, const int* in_sizes, int n_in,
                              void* d_out, int out_size, void* d_ws, size_t ws_size,
                              hipStream_t stream) {
  const float* x = (const float*)d_in[0];
  const int* ei = (const int*)d_in[1];
  const int* src = ei;
  const int* dst = ei + N_EDGES;
  const int* batch = (const int*)d_in[2];
  const float* Wl = (const float*)d_in[3];
  // d_in[4] = bl: per-column bias is exactly cancelled by BatchNorm -> unused
  const float* Wr = (const float*)d_in[5];
  const float* gamma = (const float*)d_in[6];
  const float* beta = (const float*)d_in[7];
  const float* W1 = (const float*)d_in[8];
  const float* b1 = (const float*)d_in[9];
  const float* W2 = (const float*)d_in[10];
  const float* b2 = (const float*)d_in[11];
  float* out = (float*)d_out;

  char* p = (char*)d_ws;
  const size_t H8 = (size_t)M_PAD * HID;                 // 25.6 MB
  unsigned char* hpre8 = (unsigned char*)p; p += H8;     // fp8 pre-BN activations
  unsigned char* aggr8 = (unsigned char*)p; p += H8;
  unsigned char* h8 = (unsigned char*)p;    p += H8;
  unsigned char* Wt8 = (unsigned char*)p;   p += (size_t)NLAYERS * 512 * HID;  // 0.5 MB
  int* col = (int*)p;    p += (size_t)N_EDGES * sizeof(int);              // 6.4 MB
  int* row_ptr = (int*)p; p += 400016;
  float* inv_cnt = (float*)p; p += (size_t)N_NODES * sizeof(float);
  float* psum = (float*)p;    p += (size_t)N_MBLK * 512 * sizeof(float);  // 1.6 MB
  float* tmp = (float*)p;     p += (size_t)BN_MID * 512 * sizeof(float);
  float* ss = (float*)p;      p += 512 * sizeof(float);
  float* partial = (float*)p; p += (size_t)N_GRAPHS * 8 * 256 * sizeof(float);
  uint2* ebuf = (uint2*)p;    p += (size_t)N_BUCKETS * EBUF_STRIDE * sizeof(uint2);  // 25.6 MB

  // transient CSR-build arrays overlaid into hpre8 (first written in layer-0
  // gemm, which is stream-ordered after csr_build completes)
  u64* bfill64 = (u64*)hpre8;                      // N_BUCKETS lines (padded x8)
  int* bucket_base = (int*)(bfill64 + (size_t)N_BUCKETS * 8);

  // ---- build CSR (once; edge_index is layer-invariant) ----
  hipMemsetAsync(bfill64, 0, (size_t)N_BUCKETS * 8 * sizeof(u64), stream);
  bucket_scatter<<<CSR_NBLK, CSR_BLK, 0, stream>>>(src, dst, bfill64, ebuf);
  bucket_prefix<<<1, 512, 0, stream>>>(bfill64, bucket_base, row_ptr);
  csr_build<<<N_BUCKETS, CSR_BLK, 0, stream>>>(ebuf, bfill64, bucket_base,
                                               row_ptr, inv_cnt, col);

  // ---- one-time converts ----
  convert_x8<<<N_NODES / 4, 256, 0, stream>>>((const float4*)x, (unsigned*)h8);
  convert_w8<<<(NLAYERS * 512 * HID / 4) / 256, 256, 0, stream>>>(Wl, Wr,
                                                                  (unsigned*)Wt8);

  for (int l = 0; l < NLAYERS; l++) {
    aggregate_fp8<<<N_NODES / 4, 256, 0, stream>>>(h8, row_ptr, col, inv_cnt, aggr8);
    gemm_fused_fp8<<<N_MBLK, 256, 0, stream>>>(aggr8, h8,
                                               Wt8 + (size_t)l * 512 * HID,
                                               hpre8, psum);
    bn_mid<<<BN_MID, 256, 0, stream>>>(psum, tmp);
    bn_fin<<<1, 256, 0, stream>>>(tmp, gamma + (size_t)l * HID,
                                  beta + (size_t)l * HID, ss);
    if (l < NLAYERS - 1) {
      bn_apply_h8<<<2048, 256, 0, stream>>>((const uint2*)hpre8, ss, (uint2*)h8);
    }
  }

  // layer-3 BN+ReLU fused into two-stage pooling (reads hpre8 + ss)
  pool_partial<<<dim3(N_GRAPHS, 8), 256, 0, stream>>>(hpre8, ss, batch, partial);
  pool_mlp_final<<<N_GRAPHS, 256, 0, stream>>>(partial, batch, W1, b1, W2, b2, out);
}